// Round 7
// baseline (525.874 us; speedup 1.0000x reference)
//
#include <hip/hip_runtime.h>
#include <hip/hip_bf16.h>

#define NN   50000
#define NE   600000
#define INF  602
#define HID  128
#define OUTF 41
#define NBLK 196   // ceil(NN/256)

typedef __attribute__((ext_vector_type(8))) short bf16x8;
typedef __attribute__((ext_vector_type(4))) float f32x4;

__device__ inline unsigned short f2bf(float x) {
    unsigned u = __float_as_uint(x);
    unsigned r = u + 0x7FFF + ((u >> 16) & 1);   // RNE
    return (unsigned short)(r >> 16);
}

__device__ inline bf16x8 cvt8(float4 a0, float4 a1) {
    bf16x8 h;
    h[0] = (short)f2bf(a0.x); h[1] = (short)f2bf(a0.y);
    h[2] = (short)f2bf(a0.z); h[3] = (short)f2bf(a0.w);
    h[4] = (short)f2bf(a1.x); h[5] = (short)f2bf(a1.y);
    h[6] = (short)f2bf(a1.z); h[7] = (short)f2bf(a1.w);
    return h;
}

// ---------------- degree histogram ----------------
__global__ __launch_bounds__(256) void deg_hist_k(const int* __restrict__ src,
                                                  const int* __restrict__ dst,
                                                  int* __restrict__ cnt_out,
                                                  int* __restrict__ cnt_in, int E) {
    int e = blockIdx.x * 256 + threadIdx.x;
    if (e < E) {
        atomicAdd(&cnt_out[src[e]], 1);
        atomicAdd(&cnt_in[dst[e]], 1);
    }
}

// ---------------- 3-phase scan ----------------
__global__ __launch_bounds__(256) void scan1_k(const int* __restrict__ cnt,
                                               int* __restrict__ rowptr,
                                               int* __restrict__ blockSum) {
    __shared__ int tmp[256];
    int tid = threadIdx.x;
    int i = blockIdx.x * 256 + tid;
    int v = (i < NN) ? cnt[i] : 0;
    tmp[tid] = v;
    __syncthreads();
#pragma unroll
    for (int off = 1; off < 256; off <<= 1) {
        int t = (tid >= off) ? tmp[tid - off] : 0;
        __syncthreads();
        tmp[tid] += t;
        __syncthreads();
    }
    if (i < NN) rowptr[i] = tmp[tid] - v;      // tile-exclusive
    if (tid == 255) blockSum[blockIdx.x] = tmp[255];
}

__global__ __launch_bounds__(256) void scan2_k(const int* __restrict__ blockSum,
                                               int* __restrict__ blockOff,
                                               int* __restrict__ rowptr) {
    __shared__ int tmp[256];
    int tid = threadIdx.x;
    int v = (tid < NBLK) ? blockSum[tid] : 0;
    tmp[tid] = v;
    __syncthreads();
#pragma unroll
    for (int off = 1; off < 256; off <<= 1) {
        int t = (tid >= off) ? tmp[tid - off] : 0;
        __syncthreads();
        tmp[tid] += t;
        __syncthreads();
    }
    if (tid < NBLK) blockOff[tid] = tmp[tid] - v;
    if (tid == 255) rowptr[NN] = tmp[255];
}

__global__ __launch_bounds__(256) void scan3_k(int* __restrict__ rowptr,
                                               const int* __restrict__ blockOff,
                                               int* __restrict__ wcur,
                                               const int* __restrict__ cnt_out,
                                               const int* __restrict__ cnt_in,
                                               float* __restrict__ rs_out,
                                               float* __restrict__ rs_in) {
    int i = blockIdx.x * 256 + threadIdx.x;
    if (i < NN) {
        int r = rowptr[i] + blockOff[blockIdx.x];
        rowptr[i] = r;
        wcur[i] = r;
        int co = cnt_out[i]; if (co < 1) co = 1;
        int ci = cnt_in[i];  if (ci < 1) ci = 1;
        rs_out[i] = rsqrtf((float)co);
        rs_in[i]  = rsqrtf((float)ci);
    }
}

// ---------------- CSR fill ----------------
__global__ __launch_bounds__(256) void fill_csr_k(const int* __restrict__ src,
                                                  const int* __restrict__ dst,
                                                  int* __restrict__ wcur,
                                                  int* __restrict__ csrsrc, int E) {
    int e = blockIdx.x * 256 + threadIdx.x;
    if (e < E) {
        int p = atomicAdd(&wcur[dst[e]], 1);
        csrsrc[p] = src[e];
    }
}

// ---------------- weight prep: fp32 [K][128] -> bf16 tiled [k>>3][col][k&7], K padded ----------------
__global__ __launch_bounds__(256) void prep_w_k(const float* __restrict__ W, int K,
                                                unsigned short* __restrict__ out, int total4) {
    int i = blockIdx.x * 256 + threadIdx.x;
    if (i >= total4) return;
    int col = i & 127;
    int k4 = (i >> 7) << 2;
    short4 h;
    h.x = (short)f2bf((k4 + 0 < K) ? W[(size_t)(k4 + 0) * HID + col] : 0.f);
    h.y = (short)f2bf((k4 + 1 < K) ? W[(size_t)(k4 + 1) * HID + col] : 0.f);
    h.z = (short)f2bf((k4 + 2 < K) ? W[(size_t)(k4 + 2) * HID + col] : 0.f);
    h.w = (short)f2bf((k4 + 3 < K) ? W[(size_t)(k4 + 3) * HID + col] : 0.f);
    *(short4*)&out[(size_t)(k4 >> 3) * 1024 + col * 8 + (k4 & 7)] = h;
}

// ============ gemm1 (streaming, no LDS, no barriers) ============
// H[n,128] = bf16( rs_out[row] * (A[row,:] @ W1) ), K=602 (W1t zero-padded to 640).
// Wave = 16 rows x 128 cols. A-frags loaded directly from global (16 rows x 64B
// contiguous per instr); B-frags from pre-tiled W1t (L2-resident).
__global__ __launch_bounds__(256) void gemm1_k(const float* __restrict__ A,
                                               const unsigned short* __restrict__ Wt,
                                               const float* __restrict__ rs_out,
                                               unsigned short* __restrict__ H, int n) {
    const int tid = threadIdx.x;
    const int wave = tid >> 6;
    const int lane = tid & 63;
    const int quad = lane >> 4;
    const int l16 = lane & 15;
    const int tileBase = blockIdx.x * 64 + wave * 16;
    const int arow_i = tileBase + l16;          // row this lane STREAMS (A operand)
    const bool rv = arow_i < n;
    const float* arow = A + (size_t)arow_i * INF;

    f32x4 acc[8];
#pragma unroll
    for (int j = 0; j < 8; ++j) acc[j] = (f32x4){0.f, 0.f, 0.f, 0.f};

    // 18 full K=32 steps (k = 0..575)
    for (int t = 0; t < 18; ++t) {
        int k0 = t * 32 + quad * 8;
        float4 a0 = {0.f, 0.f, 0.f, 0.f}, a1 = {0.f, 0.f, 0.f, 0.f};
        if (rv) {
            a0 = *(const float4*)(arow + k0);
            a1 = *(const float4*)(arow + k0 + 4);
        }
        bf16x8 af = cvt8(a0, a1);
        const unsigned short* bg = Wt + (size_t)(t * 4 + quad) * 1024 + l16 * 8;
#pragma unroll
        for (int nt = 0; nt < 8; ++nt) {
            bf16x8 bf = *(const bf16x8*)(bg + nt * 128);
            acc[nt] = __builtin_amdgcn_mfma_f32_16x16x32_bf16(af, bf, acc[nt], 0, 0, 0);
        }
    }
    // partial step t=18: k = 576..601 (W1t zero for k>=602)
    {
        float4 a0 = {0.f, 0.f, 0.f, 0.f}, a1 = {0.f, 0.f, 0.f, 0.f};
        if (rv) {
            int k0 = 576 + quad * 8;
            if (quad < 3) {
                a0 = *(const float4*)(arow + k0);
                a1 = *(const float4*)(arow + k0 + 4);
            } else {
                a0.x = arow[600];
                a0.y = arow[601];
            }
        }
        bf16x8 af = cvt8(a0, a1);
        const unsigned short* bg = Wt + (size_t)(18 * 4 + quad) * 1024 + l16 * 8;
#pragma unroll
        for (int nt = 0; nt < 8; ++nt) {
            bf16x8 bf = *(const bf16x8*)(bg + nt * 128);
            acc[nt] = __builtin_amdgcn_mfma_f32_16x16x32_bf16(af, bf, acc[nt], 0, 0, 0);
        }
    }

    // epilogue: C/D layout col = nt*16 + l16, row = tileBase + quad*4 + r
#pragma unroll
    for (int r = 0; r < 4; ++r) {
        int row = tileBase + quad * 4 + r;
        if (row < n) {
            float ro = rs_out[row];
#pragma unroll
            for (int nt = 0; nt < 8; ++nt)
                H[(size_t)row * HID + nt * 16 + l16] = f2bf(acc[nt][r] * ro);
        }
    }
}

// ============ gemm_hid (streaming): H[n,128] = bf16( Abf16[n,128] @ W[128,128] ) ============
__global__ __launch_bounds__(256) void gemm_hid_k(const unsigned short* __restrict__ A,
                                                  const unsigned short* __restrict__ Wt,
                                                  unsigned short* __restrict__ H, int n) {
    const int tid = threadIdx.x;
    const int wave = tid >> 6;
    const int lane = tid & 63;
    const int quad = lane >> 4;
    const int l16 = lane & 15;
    const int tileBase = blockIdx.x * 64 + wave * 16;
    const int arow_i = tileBase + l16;
    const bool rv = arow_i < n;

    f32x4 acc[8];
#pragma unroll
    for (int j = 0; j < 8; ++j) acc[j] = (f32x4){0.f, 0.f, 0.f, 0.f};

#pragma unroll 2
    for (int t = 0; t < 4; ++t) {
        bf16x8 af = (bf16x8){0, 0, 0, 0, 0, 0, 0, 0};
        if (rv) af = *(const bf16x8*)(A + (size_t)arow_i * HID + t * 32 + quad * 8);
        const unsigned short* bg = Wt + (size_t)(t * 4 + quad) * 1024 + l16 * 8;
#pragma unroll
        for (int nt = 0; nt < 8; ++nt) {
            bf16x8 bf = *(const bf16x8*)(bg + nt * 128);
            acc[nt] = __builtin_amdgcn_mfma_f32_16x16x32_bf16(af, bf, acc[nt], 0, 0, 0);
        }
    }

#pragma unroll
    for (int r = 0; r < 4; ++r) {
        int row = tileBase + quad * 4 + r;
        if (row < n) {
#pragma unroll
            for (int nt = 0; nt < 8; ++nt)
                H[(size_t)row * HID + nt * 16 + l16] = f2bf(acc[nt][r]);
        }
    }
}

// ---------------- gather + finish: H is bf16; one wave per node, lane = 2 features ----------------
__global__ __launch_bounds__(256) void gather_k(const unsigned short* __restrict__ H,
                                                const int* __restrict__ rowptr,
                                                const int* __restrict__ csrsrc,
                                                const float* __restrict__ rs_in,
                                                const float* __restrict__ rs_out,
                                                const float* __restrict__ bias,
                                                const float* __restrict__ resid,     // nullable
                                                float* __restrict__ outX,            // nullable
                                                unsigned short* __restrict__ outXs,  // nullable (bf16)
                                                int n) {
    int node = blockIdx.x * 4 + (threadIdx.x >> 6);
    if (node >= n) return;
    int lane = threadIdx.x & 63;
    const unsigned int* Hu = (const unsigned int*)H;   // ushort2 packed
    int beg = rowptr[node], end = rowptr[node + 1];
    float ax = 0.f, ay = 0.f, bx2 = 0.f, by2 = 0.f;
    int p = beg;
    for (; p + 1 < end; p += 2) {
        unsigned u0 = Hu[(size_t)csrsrc[p] * 64 + lane];
        unsigned u1 = Hu[(size_t)csrsrc[p + 1] * 64 + lane];
        ax += __uint_as_float(u0 << 16);
        ay += __uint_as_float(u0 & 0xFFFF0000u);
        bx2 += __uint_as_float(u1 << 16);
        by2 += __uint_as_float(u1 & 0xFFFF0000u);
    }
    if (p < end) {
        unsigned u = Hu[(size_t)csrsrc[p] * 64 + lane];
        ax += __uint_as_float(u << 16);
        ay += __uint_as_float(u & 0xFFFF0000u);
    }
    ax += bx2; ay += by2;
    float ri = rs_in[node];
    float vx = fmaxf(ax * ri + bias[lane * 2], 0.f);
    float vy = fmaxf(ay * ri + bias[lane * 2 + 1], 0.f);
    if (resid) {
        float2 r = *(const float2*)(resid + (size_t)node * HID + lane * 2);
        vx = fmaxf(vx + r.x, 0.f);
        vy = fmaxf(vy + r.y, 0.f);
    }
    size_t o = (size_t)node * HID + lane * 2;
    if (outX) { *(float2*)(outX + o) = make_float2(vx, vy); }
    if (outXs) {
        float ro = rs_out[node];
        ushort2 h;
        h.x = f2bf(vx * ro);
        h.y = f2bf(vy * ro);
        *(ushort2*)(outXs + o) = h;
    }
}

// ---------------- final FC: out[n,41] = X[n,128] @ Wfc + bfc ----------------
__global__ __launch_bounds__(256) void fc_k(const float* __restrict__ X,
                                            const float* __restrict__ Wfc,
                                            const float* __restrict__ bfc,
                                            float* __restrict__ out, int n) {
    __shared__ float Ws[HID * OUTF];
    __shared__ float Xs[4][HID];
    int tid = threadIdx.x;
    for (int i = tid; i < HID * OUTF; i += 256) Ws[i] = Wfc[i];
    int rowBase = blockIdx.x * 4;
    for (int i = tid; i < 4 * HID; i += 256) {
        int r = i >> 7, c = i & 127;
        int gr = rowBase + r;
        Xs[r][c] = (gr < n) ? X[(size_t)gr * HID + c] : 0.f;
    }
    __syncthreads();
    int wv = tid >> 6, lane = tid & 63;
    int row = rowBase + wv;
    if (row < n && lane < OUTF) {
        float acc = bfc[lane];
#pragma unroll 8
        for (int k = 0; k < HID; ++k) acc += Xs[wv][k] * Ws[k * OUTF + lane];
        out[(size_t)row * OUTF + lane] = acc;
    }
}

extern "C" void kernel_launch(void* const* d_in, const int* in_sizes, int n_in,
                              void* d_out, int out_size, void* d_ws, size_t ws_size,
                              hipStream_t stream) {
    const float* feat = (const float*)d_in[0];
    const int* src = (const int*)d_in[1];
    const int* dst = (const int*)d_in[2];
    const float* W1 = (const float*)d_in[3];
    const float* b1 = (const float*)d_in[4];
    const float* W2 = (const float*)d_in[5];
    const float* b2 = (const float*)d_in[6];
    const float* W3 = (const float*)d_in[7];
    const float* b3 = (const float*)d_in[8];
    const float* Wfc = (const float*)d_in[9];
    const float* bfc = (const float*)d_in[10];
    float* out = (float*)d_out;

    char* w = (char*)d_ws;
    auto alloc = [&](size_t b) -> void* {
        void* p = (void*)w;
        w += (b + 255) & ~(size_t)255;
        return p;
    };
    int* cnt_out = (int*)alloc(NN * sizeof(int));
    int* cnt_in  = (int*)alloc(NN * sizeof(int));
    int* rowptr  = (int*)alloc((NN + 1) * sizeof(int));
    int* wcur    = (int*)alloc(NN * sizeof(int));
    int* csrsrc  = (int*)alloc(NE * sizeof(int));
    int* blockSum = (int*)alloc(NBLK * sizeof(int));
    int* blockOff = (int*)alloc(NBLK * sizeof(int));
    float* rs_out = (float*)alloc(NN * sizeof(float));
    float* rs_in  = (float*)alloc(NN * sizeof(float));
    unsigned short* W1t = (unsigned short*)alloc(10 * 8192 * sizeof(unsigned short));
    unsigned short* W2t = (unsigned short*)alloc(16384 * sizeof(unsigned short));
    unsigned short* W3t = (unsigned short*)alloc(16384 * sizeof(unsigned short));
    unsigned short* Hb = (unsigned short*)alloc((size_t)NN * HID * sizeof(unsigned short));
    unsigned short* Xb = (unsigned short*)alloc((size_t)NN * HID * sizeof(unsigned short));
    float* resid = (float*)alloc((size_t)NN * HID * sizeof(float));
    float* Xfc   = (float*)alloc((size_t)NN * HID * sizeof(float));

    hipMemsetAsync(cnt_out, 0, NN * sizeof(int), stream);
    hipMemsetAsync(cnt_in, 0, NN * sizeof(int), stream);

    prep_w_k<<<80, 256, 0, stream>>>(W1, INF, W1t, 20480);   // K pad 640
    prep_w_k<<<16, 256, 0, stream>>>(W2, HID, W2t, 4096);
    prep_w_k<<<16, 256, 0, stream>>>(W3, HID, W3t, 4096);

    deg_hist_k<<<(NE + 255) / 256, 256, 0, stream>>>(src, dst, cnt_out, cnt_in, NE);
    scan1_k<<<NBLK, 256, 0, stream>>>(cnt_in, rowptr, blockSum);
    scan2_k<<<1, 256, 0, stream>>>(blockSum, blockOff, rowptr);
    scan3_k<<<NBLK, 256, 0, stream>>>(rowptr, blockOff, wcur, cnt_out, cnt_in, rs_out, rs_in);
    fill_csr_k<<<(NE + 255) / 256, 256, 0, stream>>>(src, dst, wcur, csrsrc, NE);

    const int gblk = (NN + 63) / 64;  // 782
    // Layer 1: Hb = bf16(rs_out ∘ (feat @ W1)) ; Xb = bf16(relu(agg*ri+b1) * ro)
    gemm1_k<<<gblk, 256, 0, stream>>>(feat, W1t, rs_out, Hb, NN);
    gather_k<<<(NN + 3) / 4, 256, 0, stream>>>(Hb, rowptr, csrsrc, rs_in, rs_out, b1,
                                               nullptr, nullptr, Xb, NN);
    // Layer 2 (computed once, reused for residual): resid = fp32 x2, Xb = bf16(x2 * ro)
    gemm_hid_k<<<gblk, 256, 0, stream>>>(Xb, W2t, Hb, NN);
    gather_k<<<(NN + 3) / 4, 256, 0, stream>>>(Hb, rowptr, csrsrc, rs_in, rs_out, b2,
                                               nullptr, resid, Xb, NN);
    // Layer 3: Xfc = relu(relu(agg*ri+b3) + x2)
    gemm_hid_k<<<gblk, 256, 0, stream>>>(Xb, W3t, Hb, NN);
    gather_k<<<(NN + 3) / 4, 256, 0, stream>>>(Hb, rowptr, csrsrc, rs_in, rs_out, b3,
                                               resid, Xfc, nullptr, NN);
    // FC
    fc_k<<<(NN + 3) / 4, 256, 0, stream>>>(Xfc, Wfc, bfc, out, NN);
}

// Round 9
// 514.340 us; speedup vs baseline: 1.0224x; 1.0224x over previous
//
#include <hip/hip_runtime.h>
#include <hip/hip_bf16.h>

#define NN   50000
#define NE   600000
#define INF  602
#define HID  128
#define OUTF 41
#define NBLK 196   // ceil(NN/256)

typedef __attribute__((ext_vector_type(8))) short bf16x8;
typedef __attribute__((ext_vector_type(4))) float f32x4;

__device__ inline unsigned short f2bf(float x) {
    unsigned u = __float_as_uint(x);
    unsigned r = u + 0x7FFF + ((u >> 16) & 1);   // RNE
    return (unsigned short)(r >> 16);
}

#define GLL16(gp, lp) \
    __builtin_amdgcn_global_load_lds((const __attribute__((address_space(1))) unsigned int*)(gp), \
                                     (__attribute__((address_space(3))) unsigned int*)(lp), 16, 0, 0)

// ---------------- degree histogram ----------------
__global__ __launch_bounds__(256) void deg_hist_k(const int* __restrict__ src,
                                                  const int* __restrict__ dst,
                                                  int* __restrict__ cnt_out,
                                                  int* __restrict__ cnt_in, int E) {
    int e = blockIdx.x * 256 + threadIdx.x;
    if (e < E) {
        atomicAdd(&cnt_out[src[e]], 1);
        atomicAdd(&cnt_in[dst[e]], 1);
    }
}

// ---------------- 3-phase scan ----------------
__global__ __launch_bounds__(256) void scan1_k(const int* __restrict__ cnt,
                                               int* __restrict__ rowptr,
                                               int* __restrict__ blockSum) {
    __shared__ int tmp[256];
    int tid = threadIdx.x;
    int i = blockIdx.x * 256 + tid;
    int v = (i < NN) ? cnt[i] : 0;
    tmp[tid] = v;
    __syncthreads();
#pragma unroll
    for (int off = 1; off < 256; off <<= 1) {
        int t = (tid >= off) ? tmp[tid - off] : 0;
        __syncthreads();
        tmp[tid] += t;
        __syncthreads();
    }
    if (i < NN) rowptr[i] = tmp[tid] - v;      // tile-exclusive
    if (tid == 255) blockSum[blockIdx.x] = tmp[255];
}

__global__ __launch_bounds__(256) void scan2_k(const int* __restrict__ blockSum,
                                               int* __restrict__ blockOff,
                                               int* __restrict__ rowptr) {
    __shared__ int tmp[256];
    int tid = threadIdx.x;
    int v = (tid < NBLK) ? blockSum[tid] : 0;
    tmp[tid] = v;
    __syncthreads();
#pragma unroll
    for (int off = 1; off < 256; off <<= 1) {
        int t = (tid >= off) ? tmp[tid - off] : 0;
        __syncthreads();
        tmp[tid] += t;
        __syncthreads();
    }
    if (tid < NBLK) blockOff[tid] = tmp[tid] - v;
    if (tid == 255) rowptr[NN] = tmp[255];
}

__global__ __launch_bounds__(256) void scan3_k(int* __restrict__ rowptr,
                                               const int* __restrict__ blockOff,
                                               int* __restrict__ wcur,
                                               const int* __restrict__ cnt_out,
                                               const int* __restrict__ cnt_in,
                                               float* __restrict__ rs_out,
                                               float* __restrict__ rs_in) {
    int i = blockIdx.x * 256 + threadIdx.x;
    if (i < NN) {
        int r = rowptr[i] + blockOff[blockIdx.x];
        rowptr[i] = r;
        wcur[i] = r;
        int co = cnt_out[i]; if (co < 1) co = 1;
        int ci = cnt_in[i];  if (ci < 1) ci = 1;
        rs_out[i] = rsqrtf((float)co);
        rs_in[i]  = rsqrtf((float)ci);
    }
}

// ---------------- CSR fill ----------------
__global__ __launch_bounds__(256) void fill_csr_k(const int* __restrict__ src,
                                                  const int* __restrict__ dst,
                                                  int* __restrict__ wcur,
                                                  int* __restrict__ csrsrc, int E) {
    int e = blockIdx.x * 256 + threadIdx.x;
    if (e < E) {
        int p = atomicAdd(&wcur[dst[e]], 1);
        csrsrc[p] = src[e];
    }
}

// ---------------- weight prep: fp32 [K][128] -> bf16 tiled [k>>3][col][k&7], K padded ----------------
__global__ __launch_bounds__(256) void prep_w_k(const float* __restrict__ W, int K,
                                                unsigned short* __restrict__ out, int total4) {
    int i = blockIdx.x * 256 + threadIdx.x;
    if (i >= total4) return;
    int col = i & 127;
    int k4 = (i >> 7) << 2;
    short4 h;
    h.x = (short)f2bf((k4 + 0 < K) ? W[(size_t)(k4 + 0) * HID + col] : 0.f);
    h.y = (short)f2bf((k4 + 1 < K) ? W[(size_t)(k4 + 1) * HID + col] : 0.f);
    h.z = (short)f2bf((k4 + 2 < K) ? W[(size_t)(k4 + 2) * HID + col] : 0.f);
    h.w = (short)f2bf((k4 + 3 < K) ? W[(size_t)(k4 + 3) * HID + col] : 0.f);
    *(short4*)&out[(size_t)(k4 >> 3) * 1024 + col * 8 + (k4 & 7)] = h;
}

// ============ gemm1 (chunked BK=128): H[n,128] = bf16( rs_out[row] * (A[row,:] @ W1) ) ============
// K=602 padded to 640 = 5 chunks of 128. Per chunk: B (32KB pre-tiled) via DMA,
// A staged coalesced fp32->bf16, then 4 barrier-free MFMA steps from LDS.
// 2 barriers per chunk; next chunk's A register-prefetched under compute.
__global__ __launch_bounds__(256) void gemm1_k(const float* __restrict__ A,
                                               const unsigned short* __restrict__ Wt,
                                               const float* __restrict__ rs_out,
                                               unsigned short* __restrict__ H, int n) {
    __shared__ __attribute__((aligned(16))) short As[64 * 136];   // 64 rows x 128 k, stride 136
    __shared__ __attribute__((aligned(16))) short Bs[16 * 1024];  // 16 kgroups x [col][8k]

    const int tid = threadIdx.x;
    const int wave = tid >> 6;
    const int lane = tid & 63;
    const int quad = lane >> 4;
    const int l16 = lane & 15;
    const int rowBase = blockIdx.x * 64;
    const int tileBase = rowBase + wave * 16;

    float4 apf[8];
    auto loadA = [&](int ch) {   // coalesced: 32 consecutive lanes span one row's 128 floats
        int kb = ch * 128;
#pragma unroll
        for (int c = 0; c < 8; ++c) {
            int f = c * 256 + tid;
            int row = f >> 5;
            int kc = (f & 31) << 2;
            int grow = rowBase + row;
            int gk = kb + kc;
            float4 v = {0.f, 0.f, 0.f, 0.f};
            if (grow < n) {
                if (gk + 3 < INF) {
                    v = *(const float4*)(A + (size_t)grow * INF + gk);
                } else {
                    if (gk + 0 < INF) v.x = A[(size_t)grow * INF + gk + 0];
                    if (gk + 1 < INF) v.y = A[(size_t)grow * INF + gk + 1];
                    if (gk + 2 < INF) v.z = A[(size_t)grow * INF + gk + 2];
                }
            }
            apf[c] = v;
        }
    };
    auto storeA = [&]() {
#pragma unroll
        for (int c = 0; c < 8; ++c) {
            int f = c * 256 + tid;
            int row = f >> 5;
            int kc = (f & 31) << 2;
            short4 h;
            h.x = (short)f2bf(apf[c].x); h.y = (short)f2bf(apf[c].y);
            h.z = (short)f2bf(apf[c].z); h.w = (short)f2bf(apf[c].w);
            *(short4*)&As[row * 136 + kc] = h;
        }
    };
    auto issueB = [&](int ch) {  // 32KB = 32 x 1KB wave-DMA, each wave loads its quarter
#pragma unroll
        for (int c = 0; c < 8; ++c)
            GLL16(Wt + (size_t)ch * 16384 + c * 2048 + tid * 8, &Bs[c * 2048 + tid * 8]);
    };

    f32x4 acc[8];
#pragma unroll
    for (int j = 0; j < 8; ++j) acc[j] = (f32x4){0.f, 0.f, 0.f, 0.f};

    loadA(0);
    for (int ch = 0; ch < 5; ++ch) {
        __syncthreads();             // WAR: everyone done reading previous chunk's As/Bs
        issueB(ch);
        storeA();
        __syncthreads();             // arrival: DMA drained + As visible
        if (ch + 1 < 5) loadA(ch + 1);   // prefetch next A under this chunk's compute
#pragma unroll
        for (int s = 0; s < 4; ++s) {
            bf16x8 af = *(const bf16x8*)&As[(wave * 16 + l16) * 136 + s * 32 + quad * 8];
            const short* bg = &Bs[(s * 4 + quad) * 1024 + l16 * 8];
#pragma unroll
            for (int nt = 0; nt < 8; ++nt) {
                bf16x8 bf = *(const bf16x8*)(bg + nt * 128);
                acc[nt] = __builtin_amdgcn_mfma_f32_16x16x32_bf16(af, bf, acc[nt], 0, 0, 0);
            }
        }
    }

    // epilogue: C/D layout col = nt*16 + l16, row = tileBase + quad*4 + r
#pragma unroll
    for (int r = 0; r < 4; ++r) {
        int row = tileBase + quad * 4 + r;
        if (row < n) {
            float ro = rs_out[row];
#pragma unroll
            for (int nt = 0; nt < 8; ++nt)
                H[(size_t)row * HID + nt * 16 + l16] = f2bf(acc[nt][r] * ro);
        }
    }
}

// ============ gemm_hid: H[n,128] = bf16( Abf16[n,128] @ W[128,128] ), whole-W DMA to LDS ============
__global__ __launch_bounds__(256) void gemm_hid_k(const unsigned short* __restrict__ A,
                                                  const unsigned short* __restrict__ Wt,
                                                  unsigned short* __restrict__ H, int n) {
    __shared__ __attribute__((aligned(16))) short As[64 * 136];
    __shared__ __attribute__((aligned(16))) short Bs[16384];

    const int tid = threadIdx.x;
    const int wave = tid >> 6;
    const int lane = tid & 63;
    const int quad = lane >> 4;
    const int l16 = lane & 15;
    const int wm = wave >> 1;
    const int wn = wave & 1;
    const int rowBase = blockIdx.x * 64;

#pragma unroll
    for (int c = 0; c < 8; ++c)
        GLL16(Wt + c * 2048 + tid * 8, &Bs[c * 2048 + tid * 8]);

#pragma unroll
    for (int c = 0; c < 4; ++c) {
        int f = c * 256 + tid;
        int row = f >> 4;
        int k16 = (f & 15) << 3;
        int grow = rowBase + row;
        int4 v = {0, 0, 0, 0};
        if (grow < n) v = *(const int4*)(A + (size_t)grow * HID + k16);
        *(int4*)&As[row * 136 + k16] = v;
    }
    __syncthreads();

    f32x4 acc[2][4];
#pragma unroll
    for (int i = 0; i < 2; ++i)
#pragma unroll
        for (int j = 0; j < 4; ++j) acc[i][j] = (f32x4){0.f, 0.f, 0.f, 0.f};

#pragma unroll
    for (int kq = 0; kq < 4; ++kq) {
        bf16x8 af[2], bfr[4];
#pragma unroll
        for (int mt = 0; mt < 2; ++mt)
            af[mt] = *(const bf16x8*)&As[(wm * 32 + mt * 16 + l16) * 136 + kq * 32 + quad * 8];
#pragma unroll
        for (int nt = 0; nt < 4; ++nt)
            bfr[nt] = *(const bf16x8*)&Bs[(kq * 4 + quad) * 1024 + (wn * 64 + nt * 16 + l16) * 8];
#pragma unroll
        for (int mt = 0; mt < 2; ++mt)
#pragma unroll
            for (int nt = 0; nt < 4; ++nt)
                acc[mt][nt] = __builtin_amdgcn_mfma_f32_16x16x32_bf16(af[mt], bfr[nt], acc[mt][nt], 0, 0, 0);
    }

#pragma unroll
    for (int mt = 0; mt < 2; ++mt)
#pragma unroll
        for (int r = 0; r < 4; ++r) {
            int row = rowBase + wm * 32 + mt * 16 + quad * 4 + r;
            if (row < n) {
#pragma unroll
                for (int nt = 0; nt < 4; ++nt) {
                    int col = wn * 64 + nt * 16 + l16;
                    H[(size_t)row * HID + col] = f2bf(acc[mt][nt][r]);
                }
            }
        }
}

// ---------------- gather + finish: H is bf16; one wave per node, lane = 2 features ----------------
__global__ __launch_bounds__(256) void gather_k(const unsigned short* __restrict__ H,
                                                const int* __restrict__ rowptr,
                                                const int* __restrict__ csrsrc,
                                                const float* __restrict__ rs_in,
                                                const float* __restrict__ rs_out,
                                                const float* __restrict__ bias,
                                                const float* __restrict__ resid,     // nullable
                                                float* __restrict__ outX,            // nullable
                                                unsigned short* __restrict__ outXs,  // nullable (bf16)
                                                int n) {
    int node = blockIdx.x * 4 + (threadIdx.x >> 6);
    if (node >= n) return;
    int lane = threadIdx.x & 63;
    const unsigned int* Hu = (const unsigned int*)H;   // ushort2 packed
    int beg = rowptr[node], end = rowptr[node + 1];
    float ax = 0.f, ay = 0.f, bx2 = 0.f, by2 = 0.f;
    int p = beg;
    for (; p + 1 < end; p += 2) {
        unsigned u0 = Hu[(size_t)csrsrc[p] * 64 + lane];
        unsigned u1 = Hu[(size_t)csrsrc[p + 1] * 64 + lane];
        ax += __uint_as_float(u0 << 16);
        ay += __uint_as_float(u0 & 0xFFFF0000u);
        bx2 += __uint_as_float(u1 << 16);
        by2 += __uint_as_float(u1 & 0xFFFF0000u);
    }
    if (p < end) {
        unsigned u = Hu[(size_t)csrsrc[p] * 64 + lane];
        ax += __uint_as_float(u << 16);
        ay += __uint_as_float(u & 0xFFFF0000u);
    }
    ax += bx2; ay += by2;
    float ri = rs_in[node];
    float vx = fmaxf(ax * ri + bias[lane * 2], 0.f);
    float vy = fmaxf(ay * ri + bias[lane * 2 + 1], 0.f);
    if (resid) {
        float2 r = *(const float2*)(resid + (size_t)node * HID + lane * 2);
        vx = fmaxf(vx + r.x, 0.f);
        vy = fmaxf(vy + r.y, 0.f);
    }
    size_t o = (size_t)node * HID + lane * 2;
    if (outX) { *(float2*)(outX + o) = make_float2(vx, vy); }
    if (outXs) {
        float ro = rs_out[node];
        ushort2 h;
        h.x = f2bf(vx * ro);
        h.y = f2bf(vy * ro);
        *(ushort2*)(outXs + o) = h;
    }
}

// ---------------- final FC: out[n,41] = X[n,128] @ Wfc + bfc ----------------
__global__ __launch_bounds__(256) void fc_k(const float* __restrict__ X,
                                            const float* __restrict__ Wfc,
                                            const float* __restrict__ bfc,
                                            float* __restrict__ out, int n) {
    __shared__ float Ws[HID * OUTF];
    __shared__ float Xs[4][HID];
    int tid = threadIdx.x;
    for (int i = tid; i < HID * OUTF; i += 256) Ws[i] = Wfc[i];
    int rowBase = blockIdx.x * 4;
    for (int i = tid; i < 4 * HID; i += 256) {
        int r = i >> 7, c = i & 127;
        int gr = rowBase + r;
        Xs[r][c] = (gr < n) ? X[(size_t)gr * HID + c] : 0.f;
    }
    __syncthreads();
    int wv = tid >> 6, lane = tid & 63;
    int row = rowBase + wv;
    if (row < n && lane < OUTF) {
        float acc = bfc[lane];
#pragma unroll 8
        for (int k = 0; k < HID; ++k) acc += Xs[wv][k] * Ws[k * OUTF + lane];
        out[(size_t)row * OUTF + lane] = acc;
    }
}

extern "C" void kernel_launch(void* const* d_in, const int* in_sizes, int n_in,
                              void* d_out, int out_size, void* d_ws, size_t ws_size,
                              hipStream_t stream) {
    const float* feat = (const float*)d_in[0];
    const int* src = (const int*)d_in[1];
    const int* dst = (const int*)d_in[2];
    const float* W1 = (const float*)d_in[3];
    const float* b1 = (const float*)d_in[4];
    const float* W2 = (const float*)d_in[5];
    const float* b2 = (const float*)d_in[6];
    const float* W3 = (const float*)d_in[7];
    const float* b3 = (const float*)d_in[8];
    const float* Wfc = (const float*)d_in[9];
    const float* bfc = (const float*)d_in[10];
    float* out = (float*)d_out;

    char* w = (char*)d_ws;
    auto alloc = [&](size_t b) -> void* {
        void* p = (void*)w;
        w += (b + 255) & ~(size_t)255;
        return p;
    };
    int* cnt_out = (int*)alloc(NN * sizeof(int));
    int* cnt_in  = (int*)alloc(NN * sizeof(int));
    int* rowptr  = (int*)alloc((NN + 1) * sizeof(int));
    int* wcur    = (int*)alloc(NN * sizeof(int));
    int* csrsrc  = (int*)alloc(NE * sizeof(int));
    int* blockSum = (int*)alloc(NBLK * sizeof(int));
    int* blockOff = (int*)alloc(NBLK * sizeof(int));
    float* rs_out = (float*)alloc(NN * sizeof(float));
    float* rs_in  = (float*)alloc(NN * sizeof(float));
    unsigned short* W1t = (unsigned short*)alloc(10 * 8192 * sizeof(unsigned short));
    unsigned short* W2t = (unsigned short*)alloc(16384 * sizeof(unsigned short));
    unsigned short* W3t = (unsigned short*)alloc(16384 * sizeof(unsigned short));
    unsigned short* Hb = (unsigned short*)alloc((size_t)NN * HID * sizeof(unsigned short));
    unsigned short* Xb = (unsigned short*)alloc((size_t)NN * HID * sizeof(unsigned short));
    float* resid = (float*)alloc((size_t)NN * HID * sizeof(float));
    float* Xfc   = (float*)alloc((size_t)NN * HID * sizeof(float));

    hipMemsetAsync(cnt_out, 0, NN * sizeof(int), stream);
    hipMemsetAsync(cnt_in, 0, NN * sizeof(int), stream);

    prep_w_k<<<80, 256, 0, stream>>>(W1, INF, W1t, 20480);   // K pad 640
    prep_w_k<<<16, 256, 0, stream>>>(W2, HID, W2t, 4096);
    prep_w_k<<<16, 256, 0, stream>>>(W3, HID, W3t, 4096);

    deg_hist_k<<<(NE + 255) / 256, 256, 0, stream>>>(src, dst, cnt_out, cnt_in, NE);
    scan1_k<<<NBLK, 256, 0, stream>>>(cnt_in, rowptr, blockSum);
    scan2_k<<<1, 256, 0, stream>>>(blockSum, blockOff, rowptr);
    scan3_k<<<NBLK, 256, 0, stream>>>(rowptr, blockOff, wcur, cnt_out, cnt_in, rs_out, rs_in);
    fill_csr_k<<<(NE + 255) / 256, 256, 0, stream>>>(src, dst, wcur, csrsrc, NE);

    const int gblk = (NN + 63) / 64;  // 782
    // Layer 1: Hb = bf16(rs_out ∘ (feat @ W1)) ; Xb = bf16(relu(agg*ri+b1) * ro)
    gemm1_k<<<gblk, 256, 0, stream>>>(feat, W1t, rs_out, Hb, NN);
    gather_k<<<(NN + 3) / 4, 256, 0, stream>>>(Hb, rowptr, csrsrc, rs_in, rs_out, b1,
                                               nullptr, nullptr, Xb, NN);
    // Layer 2 (computed once, reused for residual): resid = fp32 x2, Xb = bf16(x2 * ro)
    gemm_hid_k<<<gblk, 256, 0, stream>>>(Xb, W2t, Hb, NN);
    gather_k<<<(NN + 3) / 4, 256, 0, stream>>>(Hb, rowptr, csrsrc, rs_in, rs_out, b2,
                                               nullptr, resid, Xb, NN);
    // Layer 3: Xfc = relu(relu(agg*ri+b3) + x2)
    gemm_hid_k<<<gblk, 256, 0, stream>>>(Xb, W3t, Hb, NN);
    gather_k<<<(NN + 3) / 4, 256, 0, stream>>>(Hb, rowptr, csrsrc, rs_in, rs_out, b3,
                                               resid, Xfc, nullptr, NN);
    // FC
    fc_k<<<(NN + 3) / 4, 256, 0, stream>>>(Xfc, Wfc, bfc, out, NN);
}